// Round 6
// baseline (336.767 us; speedup 1.0000x reference)
//
#include <hip/hip_runtime.h>

// KPMiniMod round 6:
//  Phase 1 (mod_mlp_mfma): bf16 MFMA MLP -> modw + bf16 feature table fb.
//    Round-6: 500 blocks, ONE tile per wave (was 250 blocks x 2 serial tiles,
//    ~3% occupancy, all latency exposed -> 90us).
//  Phase 2 (kp_gather_bf16): influence + gathers from fb + aggregate.
//    Round-6: 8 blocks/CU, software-pipelined 16-deep pure-load chunks,
//    non-temporal streams (modw/inds/out) so the 4.1MB fb table stays L2-resident
//    (round-5: 206MB FETCH = 79% miss on an L2-sized table -> stream thrash).
//  Fallback: round-3/4 proven f32 path if ws too small.

#define MQ 32000

typedef unsigned short u16;
typedef unsigned int   u32;
typedef __attribute__((ext_vector_type(8))) short bf16x8;
typedef __attribute__((ext_vector_type(4))) float f32x4;

__device__ __forceinline__ float rlf(float v, int l) {
    return __int_as_float(__builtin_amdgcn_readlane(__float_as_int(v), l));
}
__device__ __forceinline__ int rli(int v, int l) {
    return __builtin_amdgcn_readlane(v, l);
}
__device__ __forceinline__ u16 f2bf(float x) {   // f32 -> bf16 RTNE
    u32 u = __float_as_uint(x);
    return (u16)((u + 0x7FFFu + ((u >> 16) & 1u)) >> 16);
}
__device__ __forceinline__ float bf2f(u16 b) {
    return __uint_as_float(((u32)b) << 16);
}

// ---------------------------------------------------------------- phase 1 (MFMA)
// Per wave: 16 query rows, one tile. A row = lane&15, k = (lane>>4)*8+[0..8).
// C/D: col = lane&15, row = (lane>>4)*4+reg  [m89-verified layout].
__global__ __launch_bounds__(256, 2)
void mod_mlp_mfma(const float* __restrict__ s_feats,
                  const float* __restrict__ w1,
                  const float* __restrict__ b1,
                  const float* __restrict__ w2,
                  float* __restrict__ modw,   // (M,120) sigmoid applied
                  u16*   __restrict__ fb)     // (M,64) bf16 feature table
{
    __shared__ u16 w1b[64 * 64];    // 8 KB
    __shared__ u16 w2b[64 * 128];   // 16 KB (cols 120..127 zero)
    __shared__ u16 hb[4][16 * 64];  // 8 KB, wave-private H transpose buffers

    const int tid = threadIdx.x;
    for (int i = tid; i < 64 * 64; i += 256) w1b[i] = f2bf(w1[i]);
    for (int i = tid; i < 64 * 128; i += 256) {
        int k = i >> 7, j = i & 127;
        w2b[i] = (j < 120) ? f2bf(w2[k * 120 + j]) : (u16)0;
    }
    __syncthreads();

    const int lane = tid & 63;
    const int wid  = tid >> 6;
    const int jj   = lane & 15;
    const int rb   = (lane >> 4) * 8;
    const int rowC = (lane >> 4) * 4;

    // one-time B fragments
    bf16x8 b1f[4][2];
    #pragma unroll
    for (int nt = 0; nt < 4; ++nt)
        #pragma unroll
        for (int kk = 0; kk < 2; ++kk)
            #pragma unroll
            for (int r = 0; r < 8; ++r)
                b1f[nt][kk][r] = (short)w1b[(kk * 32 + rb + r) * 64 + nt * 16 + jj];

    bf16x8 b2f[8][2];
    #pragma unroll
    for (int nt = 0; nt < 8; ++nt)
        #pragma unroll
        for (int kk = 0; kk < 2; ++kk)
            #pragma unroll
            for (int r = 0; r < 8; ++r)
                b2f[nt][kk][r] = (short)w2b[(kk * 32 + rb + r) * 128 + nt * 16 + jj];

    float b1v[4];
    #pragma unroll
    for (int nt = 0; nt < 4; ++nt) b1v[nt] = b1[nt * 16 + jj];

    u16* hrow = &hb[wid][0];
    const int t = blockIdx.x * 4 + wid;       // 0..1999, one tile per wave
    const int m0 = t * 16;

    // A fragments: rows m0+jj, k = rb..rb+7 and 32+rb..32+rb+7
    const float* ar = s_feats + (size_t)(m0 + jj) * 64 + rb;
    float4 v0 = *(const float4*)(ar);
    float4 v1 = *(const float4*)(ar + 4);
    float4 v2 = *(const float4*)(ar + 32);
    float4 v3 = *(const float4*)(ar + 36);
    bf16x8 a0, a1;
    a0[0] = (short)f2bf(v0.x); a0[1] = (short)f2bf(v0.y);
    a0[2] = (short)f2bf(v0.z); a0[3] = (short)f2bf(v0.w);
    a0[4] = (short)f2bf(v1.x); a0[5] = (short)f2bf(v1.y);
    a0[6] = (short)f2bf(v1.z); a0[7] = (short)f2bf(v1.w);
    a1[0] = (short)f2bf(v2.x); a1[1] = (short)f2bf(v2.y);
    a1[2] = (short)f2bf(v2.z); a1[3] = (short)f2bf(v2.w);
    a1[4] = (short)f2bf(v3.x); a1[5] = (short)f2bf(v3.y);
    a1[6] = (short)f2bf(v3.z); a1[7] = (short)f2bf(v3.w);

    *(bf16x8*)(fb + (size_t)(m0 + jj) * 64 + rb)      = a0;
    *(bf16x8*)(fb + (size_t)(m0 + jj) * 64 + 32 + rb) = a1;

    // GEMM1: H = leaky(F @ W1 + b1)
    f32x4 acc[4];
    #pragma unroll
    for (int nt = 0; nt < 4; ++nt) {
        f32x4 z = {0.f, 0.f, 0.f, 0.f};
        z = __builtin_amdgcn_mfma_f32_16x16x32_bf16(a0, b1f[nt][0], z, 0, 0, 0);
        acc[nt] = __builtin_amdgcn_mfma_f32_16x16x32_bf16(a1, b1f[nt][1], z, 0, 0, 0);
    }
    #pragma unroll
    for (int nt = 0; nt < 4; ++nt) {
        #pragma unroll
        for (int r = 0; r < 4; ++r) {
            float h = acc[nt][r] + b1v[nt];
            h = (h >= 0.f) ? h : 0.1f * h;
            hrow[(rowC + r) * 64 + nt * 16 + jj] = f2bf(h);
        }
    }
    bf16x8 ha0 = *(bf16x8*)(hrow + jj * 64 + rb);
    bf16x8 ha1 = *(bf16x8*)(hrow + jj * 64 + 32 + rb);

    // GEMM2 + sigmoid + store
    #pragma unroll
    for (int nt = 0; nt < 8; ++nt) {
        f32x4 z = {0.f, 0.f, 0.f, 0.f};
        z = __builtin_amdgcn_mfma_f32_16x16x32_bf16(ha0, b2f[nt][0], z, 0, 0, 0);
        f32x4 c2 = __builtin_amdgcn_mfma_f32_16x16x32_bf16(ha1, b2f[nt][1], z, 0, 0, 0);
        const int j = nt * 16 + jj;
        if (j < 120) {
            #pragma unroll
            for (int r = 0; r < 4; ++r)
                modw[(size_t)(m0 + rowC + r) * 120 + j] = 1.f / (1.f + __expf(-c2[r]));
        }
    }
}

// ---------------------------------------------------------------- phase 2 helpers
__device__ __forceinline__ void load16(u16* g, int pk, int base, const u16* fb, int c) {
    #pragma unroll
    for (int h = 0; h < 16; ++h)
        g[h] = fb[(size_t)((u32)rli(pk, base + h) >> 4) * 64 + c];
}

__device__ __forceinline__ float red16(const u16* g, int pk, float infl_v, int base,
                                       float vA, float vB, const float* wt_lds,
                                       int c, int u) {
    float p0 = 0.f, p1 = 0.f, p2 = 0.f, p3 = 0.f;
    #pragma unroll
    for (int h = 0; h < 16; h += 4) {
        #pragma unroll
        for (int j = 0; j < 4; ++j) {
            const int s = rli(pk, base + h + j);
            const int kh = s & 15;
            const float fl = rlf(infl_v, base + h + j);
            const float sv = (kh < 8) ? __shfl(vA, (kh << 3) + u)
                                      : __shfl(vB, ((kh - 8) << 3) + u);
            const float w = wt_lds[(kh << 6) + c] * sv * fl;
            float& p = (j == 0) ? p0 : (j == 1) ? p1 : (j == 2) ? p2 : p3;
            p = fmaf(bf2f(g[h + j]), w, p);
        }
    }
    return (p0 + p1) + (p2 + p3);
}

// ---------------------------------------------------------------- phase 2
__global__ __launch_bounds__(256, 8)
void kp_gather_bf16(const float* __restrict__ q_pts,
                    const float* __restrict__ s_pts,
                    const u16*   __restrict__ fb,
                    const int*   __restrict__ neighb_inds,
                    const float* __restrict__ kpts,
                    const float* __restrict__ weights,
                    const float* __restrict__ modw,
                    float* __restrict__ out)
{
    __shared__ float wt_lds[15 * 64];
    const int tid = threadIdx.x;
    if (tid < 240) ((float4*)wt_lds)[tid] = ((const float4*)weights)[tid];
    __syncthreads();

    const int lane = tid & 63;
    const int wid  = tid >> 6;
    const int c    = lane;
    const int u    = c >> 3;
    const int pair = blockIdx.x * 4 + wid;   // 16000 pairs exactly
    const int m0 = pair * 2;

    // ---- influence: lane = q*32 + h ----
    const int q = lane >> 5;
    const int m = m0 + q;
    const int ind = __builtin_nontemporal_load(&neighb_inds[(size_t)m0 * 32 + lane]);
    const float qx = q_pts[m * 3 + 0];
    const float qy = q_pts[m * 3 + 1];
    const float qz = q_pts[m * 3 + 2];
    const float px = s_pts[(size_t)ind * 3 + 0] - qx;
    const float py = s_pts[(size_t)ind * 3 + 1] - qy;
    const float pz = s_pts[(size_t)ind * 3 + 2] - qz;
    float best = 1e30f; int bk = 0;
    #pragma unroll
    for (int k = 0; k < 15; ++k) {
        float ex = px - kpts[k * 3 + 0];
        float ey = py - kpts[k * 3 + 1];
        float ez = pz - kpts[k * 3 + 2];
        float d2 = fmaf(ex, ex, fmaf(ey, ey, ez * ez));
        if (d2 < best) { best = d2; bk = k; }   // first-min (argmin rule)
    }
    const float infl = fmaxf(0.f, 1.f - sqrtf(best));
    const int pk = (ind << 4) | bk;

    // ---- modulation rows (nt: stream, read-once) ----
    const size_t mb0 = (size_t)m0 * 120, mb1 = mb0 + 120;
    const float vA0 = __builtin_nontemporal_load(&modw[mb0 + c]);
    const float vB0 = (c < 56) ? __builtin_nontemporal_load(&modw[mb0 + 64 + c]) : 0.f;
    const float vA1 = __builtin_nontemporal_load(&modw[mb1 + c]);
    const float vB1 = (c < 56) ? __builtin_nontemporal_load(&modw[mb1 + 64 + c]) : 0.f;

    // ---- software-pipelined 16-deep chunks: C0,C1 in flight; load C2 while reducing ----
    u16 gA[16], gB[16];
    load16(gA, pk, 0,  fb, c);
    load16(gB, pk, 16, fb, c);
    const float a0 = red16(gA, pk, infl, 0,  vA0, vB0, wt_lds, c, u);
    load16(gA, pk, 32, fb, c);
    const float a1 = red16(gB, pk, infl, 16, vA0, vB0, wt_lds, c, u);
    load16(gB, pk, 48, fb, c);
    const float b0 = red16(gA, pk, infl, 32, vA1, vB1, wt_lds, c, u);
    const float b1r = red16(gB, pk, infl, 48, vA1, vB1, wt_lds, c, u);

    __builtin_nontemporal_store(a0 + a1, &out[(size_t)m0 * 64 + c]);
    __builtin_nontemporal_store(b0 + b1r, &out[(size_t)(m0 + 1) * 64 + c]);
}

// ------------------- fallback tier: round-3/4 proven f32 path -------------------
__global__ __launch_bounds__(256, 3)
void mod_mlp(const float* __restrict__ s_feats,
             const float* __restrict__ w1,
             const float* __restrict__ b1,
             const float* __restrict__ w2,
             float* __restrict__ modw)
{
    __shared__ float w1_lds[64 * 64];
    __shared__ float w2_lds[64 * 120 + 8];

    const int tid = threadIdx.x;
    {
        const float4* s1 = (const float4*)w1;
        float4* d1 = (float4*)w1_lds;
        #pragma unroll
        for (int i = 0; i < 4; ++i) d1[tid + 256 * i] = s1[tid + 256 * i];
        const float4* s2 = (const float4*)w2;
        float4* d2 = (float4*)w2_lds;
        for (int i = tid; i < (64 * 120) / 4; i += 256) d2[i] = s2[i];
        if (tid < 8) w2_lds[64 * 120 + tid] = 0.f;
    }
    __syncthreads();

    const int lane = tid & 63;
    const int wid  = tid >> 6;
    const int c    = lane;
    const int nwaves = gridDim.x * 4;
    const int gwave  = blockIdx.x * 4 + wid;
    const float b1v = b1[c];
    const int cB = 64 + ((c < 56) ? c : 55);

    for (int pair = gwave; pair * 2 < MQ; pair += nwaves) {
        const int m0 = pair * 2;
        float f0 = s_feats[(size_t)m0 * 64 + c];
        float f1 = s_feats[(size_t)(m0 + 1) * 64 + c];
        float h0a = b1v, h0b = 0.f, h1a = b1v, h1b = 0.f;
        #pragma unroll
        for (int i = 0; i < 64; i += 2) {
            float wa = w1_lds[i * 64 + c];
            float wb = w1_lds[(i + 1) * 64 + c];
            h0a = fmaf(rlf(f0, i), wa, h0a);
            h0b = fmaf(rlf(f0, i + 1), wb, h0b);
            h1a = fmaf(rlf(f1, i), wa, h1a);
            h1b = fmaf(rlf(f1, i + 1), wb, h1b);
        }
        float h0 = h0a + h0b, h1 = h1a + h1b;
        h0 = (h0 >= 0.f) ? h0 : 0.1f * h0;
        h1 = (h1 >= 0.f) ? h1 : 0.1f * h1;
        float a00 = 0.f, a01 = 0.f, a10 = 0.f, a11 = 0.f;
        #pragma unroll
        for (int i = 0; i < 64; ++i) {
            float wA = w2_lds[i * 120 + c];
            float wB = w2_lds[i * 120 + cB];
            float s0 = rlf(h0, i);
            float s1 = rlf(h1, i);
            a00 = fmaf(s0, wA, a00);
            a01 = fmaf(s0, wB, a01);
            a10 = fmaf(s1, wA, a10);
            a11 = fmaf(s1, wB, a11);
        }
        modw[(size_t)m0 * 120 + c]       = 1.f / (1.f + __expf(-a00));
        modw[(size_t)(m0 + 1) * 120 + c] = 1.f / (1.f + __expf(-a10));
        if (c < 56) {
            modw[(size_t)m0 * 120 + 64 + c]       = 1.f / (1.f + __expf(-a01));
            modw[(size_t)(m0 + 1) * 120 + 64 + c] = 1.f / (1.f + __expf(-a11));
        }
    }
}

__global__ __launch_bounds__(256, 4)
void kp_gather(const float* __restrict__ q_pts,
               const float* __restrict__ s_pts,
               const float* __restrict__ s_feats,
               const int*   __restrict__ neighb_inds,
               const float* __restrict__ kpts,
               const float* __restrict__ weights,
               const float* __restrict__ modw,
               float* __restrict__ out)
{
    __shared__ float wt_lds[15 * 64];
    const int tid = threadIdx.x;
    if (tid < 240) ((float4*)wt_lds)[tid] = ((const float4*)weights)[tid];
    __syncthreads();

    const int lane = tid & 63;
    const int wid  = tid >> 6;
    const int c    = lane;
    const int u    = c >> 3;
    const int pair = blockIdx.x * 4 + wid;
    const int m0 = pair * 2;

    const int q = lane >> 5;
    const int m = m0 + q;
    const int ind = neighb_inds[(size_t)m0 * 32 + lane];
    const float qx = q_pts[m * 3 + 0];
    const float qy = q_pts[m * 3 + 1];
    const float qz = q_pts[m * 3 + 2];
    const float px = s_pts[(size_t)ind * 3 + 0] - qx;
    const float py = s_pts[(size_t)ind * 3 + 1] - qy;
    const float pz = s_pts[(size_t)ind * 3 + 2] - qz;
    float best = 1e30f; int bk = 0;
    #pragma unroll
    for (int k = 0; k < 15; ++k) {
        float ex = px - kpts[k * 3 + 0];
        float ey = py - kpts[k * 3 + 1];
        float ez = pz - kpts[k * 3 + 2];
        float d2 = fmaf(ex, ex, fmaf(ey, ey, ez * ez));
        if (d2 < best) { best = d2; bk = k; }
    }
    const float infl = fmaxf(0.f, 1.f - sqrtf(best));
    const int pk = (ind << 4) | bk;

    const size_t mb0 = (size_t)m0 * 120, mb1 = mb0 + 120;
    const float vA0 = modw[mb0 + c];
    const float vB0 = (c < 56) ? modw[mb0 + 64 + c] : 0.f;
    const float vA1 = modw[mb1 + c];
    const float vB1 = (c < 56) ? modw[mb1 + 64 + c] : 0.f;

    float fv0[32], fv1[32];
    #pragma unroll
    for (int h = 0; h < 32; ++h)
        fv0[h] = s_feats[(size_t)(rli(pk, h) >> 4) * 64 + c];
    #pragma unroll
    for (int h = 0; h < 32; ++h)
        fv1[h] = s_feats[(size_t)(rli(pk, 32 + h) >> 4) * 64 + c];

    float p0 = 0.f, p1 = 0.f, p2 = 0.f, p3 = 0.f;
    #pragma unroll
    for (int h = 0; h < 32; h += 4) {
        #pragma unroll
        for (int j = 0; j < 4; ++j) {
            const int s = rli(pk, h + j);
            const int kh = s & 15;
            const float fl = rlf(infl, h + j);
            const float sv = (kh < 8) ? __shfl(vA0, (kh << 3) + u)
                                      : __shfl(vB0, ((kh - 8) << 3) + u);
            const float w = wt_lds[(kh << 6) + c] * sv * fl;
            float& p = (j == 0) ? p0 : (j == 1) ? p1 : (j == 2) ? p2 : p3;
            p = fmaf(fv0[h + j], w, p);
        }
    }
    const float acc0 = (p0 + p1) + (p2 + p3);

    float r0 = 0.f, r1 = 0.f, r2 = 0.f, r3 = 0.f;
    #pragma unroll
    for (int h = 0; h < 32; h += 4) {
        #pragma unroll
        for (int j = 0; j < 4; ++j) {
            const int s = rli(pk, 32 + h + j);
            const int kh = s & 15;
            const float fl = rlf(infl, 32 + h + j);
            const float sv = (kh < 8) ? __shfl(vA1, (kh << 3) + u)
                                      : __shfl(vB1, ((kh - 8) << 3) + u);
            const float w = wt_lds[(kh << 6) + c] * sv * fl;
            float& p = (j == 0) ? r0 : (j == 1) ? r1 : (j == 2) ? r2 : r3;
            p = fmaf(fv1[h + j], w, p);
        }
    }
    const float acc1 = (r0 + r1) + (r2 + r3);

    out[(size_t)m0 * 64 + c]       = acc0;
    out[(size_t)(m0 + 1) * 64 + c] = acc1;
}

extern "C" void kernel_launch(void* const* d_in, const int* in_sizes, int n_in,
                              void* d_out, int out_size, void* d_ws, size_t ws_size,
                              hipStream_t stream) {
    const float* q_pts       = (const float*)d_in[0];
    const float* s_pts       = (const float*)d_in[1];
    const float* s_feats     = (const float*)d_in[2];
    const int*   neighb_inds = (const int*)d_in[3];
    const float* kpts        = (const float*)d_in[4];
    const float* weights     = (const float*)d_in[5];
    const float* w1          = (const float*)d_in[6];
    const float* b1          = (const float*)d_in[7];
    const float* w2          = (const float*)d_in[8];
    float* out = (float*)d_out;

    const size_t needFB   = (size_t)MQ * 64 * sizeof(u16);     // 4.096 MB
    const size_t needMODW = (size_t)MQ * 120 * sizeof(float);  // 15.36 MB
    if (ws_size >= needFB + needMODW) {
        u16*   fb   = (u16*)d_ws;
        float* modw = (float*)((char*)d_ws + needFB);
        mod_mlp_mfma<<<500, 256, 0, stream>>>(s_feats, w1, b1, w2, modw, fb);
        kp_gather_bf16<<<MQ / 8, 256, 0, stream>>>(q_pts, s_pts, fb, neighb_inds,
                                                   kpts, weights, modw, out);
    } else {
        float* modw = (float*)d_ws;
        mod_mlp<<<768, 256, 0, stream>>>(s_feats, w1, b1, w2, modw);
        kp_gather<<<MQ / 8, 256, 0, stream>>>(q_pts, s_pts, s_feats, neighb_inds,
                                              kpts, weights, modw, out);
    }
}

// Round 8
// 116.923 us; speedup vs baseline: 2.8802x; 2.8802x over previous
//
#include <hip/hip_runtime.h>

// KPMiniMod round 8 (= round 7 + compile fix: nontemporal_store needs clang
// ext-vector, not HIP float4).
//  Phase 1 (mod_mlp_mfma): bf16 MFMA MLP -> modw + fb.
//  Phase 2 (kp_gather_v3): lane map cdiv=lane&7 (8 channels), hl=lane>>3
//    (neighbor) -> ONE dwordx4 per 8 rows (8x fewer VMEM insts). fb loads
//    issue before influence loop; h-reduction = 3-step shfl_xor butterfly.
//  Fallback: proven f32 path if ws too small.

#define MQ 32000

typedef unsigned short u16;
typedef unsigned int   u32;
typedef __attribute__((ext_vector_type(8))) short bf16x8;
typedef __attribute__((ext_vector_type(4))) float f32x4;

__device__ __forceinline__ float rlf(float v, int l) {
    return __int_as_float(__builtin_amdgcn_readlane(__float_as_int(v), l));
}
__device__ __forceinline__ int rli(int v, int l) {
    return __builtin_amdgcn_readlane(v, l);
}
__device__ __forceinline__ u16 f2bf(float x) {   // f32 -> bf16 RTNE
    u32 u = __float_as_uint(x);
    return (u16)((u + 0x7FFFu + ((u >> 16) & 1u)) >> 16);
}
__device__ __forceinline__ float bf2f(u16 b) {
    return __uint_as_float(((u32)b) << 16);
}

// ---------------------------------------------------------------- phase 1 (MFMA)
// Per wave: 16 query rows, one tile. C/D: col=lane&15, row=(lane>>4)*4+reg.
__global__ __launch_bounds__(256, 2)
void mod_mlp_mfma(const float* __restrict__ s_feats,
                  const float* __restrict__ w1,
                  const float* __restrict__ b1,
                  const float* __restrict__ w2,
                  float* __restrict__ modw,   // (M,120) sigmoid applied
                  u16*   __restrict__ fb)     // (M,64) bf16 feature table
{
    __shared__ u16 w1b[64 * 64];
    __shared__ u16 w2b[64 * 128];
    __shared__ u16 hb[4][16 * 64];

    const int tid = threadIdx.x;
    for (int i = tid; i < 64 * 64; i += 256) w1b[i] = f2bf(w1[i]);
    for (int i = tid; i < 64 * 128; i += 256) {
        int k = i >> 7, j = i & 127;
        w2b[i] = (j < 120) ? f2bf(w2[k * 120 + j]) : (u16)0;
    }
    __syncthreads();

    const int lane = tid & 63;
    const int wid  = tid >> 6;
    const int jj   = lane & 15;
    const int rb   = (lane >> 4) * 8;
    const int rowC = (lane >> 4) * 4;

    bf16x8 b1f[4][2];
    #pragma unroll
    for (int nt = 0; nt < 4; ++nt)
        #pragma unroll
        for (int kk = 0; kk < 2; ++kk)
            #pragma unroll
            for (int r = 0; r < 8; ++r)
                b1f[nt][kk][r] = (short)w1b[(kk * 32 + rb + r) * 64 + nt * 16 + jj];

    bf16x8 b2f[8][2];
    #pragma unroll
    for (int nt = 0; nt < 8; ++nt)
        #pragma unroll
        for (int kk = 0; kk < 2; ++kk)
            #pragma unroll
            for (int r = 0; r < 8; ++r)
                b2f[nt][kk][r] = (short)w2b[(kk * 32 + rb + r) * 128 + nt * 16 + jj];

    float b1v[4];
    #pragma unroll
    for (int nt = 0; nt < 4; ++nt) b1v[nt] = b1[nt * 16 + jj];

    u16* hrow = &hb[wid][0];
    const int t = blockIdx.x * 4 + wid;       // one 16-row tile per wave
    const int m0 = t * 16;

    const float* ar = s_feats + (size_t)(m0 + jj) * 64 + rb;
    float4 v0 = *(const float4*)(ar);
    float4 v1 = *(const float4*)(ar + 4);
    float4 v2 = *(const float4*)(ar + 32);
    float4 v3 = *(const float4*)(ar + 36);
    bf16x8 a0, a1;
    a0[0] = (short)f2bf(v0.x); a0[1] = (short)f2bf(v0.y);
    a0[2] = (short)f2bf(v0.z); a0[3] = (short)f2bf(v0.w);
    a0[4] = (short)f2bf(v1.x); a0[5] = (short)f2bf(v1.y);
    a0[6] = (short)f2bf(v1.z); a0[7] = (short)f2bf(v1.w);
    a1[0] = (short)f2bf(v2.x); a1[1] = (short)f2bf(v2.y);
    a1[2] = (short)f2bf(v2.z); a1[3] = (short)f2bf(v2.w);
    a1[4] = (short)f2bf(v3.x); a1[5] = (short)f2bf(v3.y);
    a1[6] = (short)f2bf(v3.z); a1[7] = (short)f2bf(v3.w);

    *(bf16x8*)(fb + (size_t)(m0 + jj) * 64 + rb)      = a0;
    *(bf16x8*)(fb + (size_t)(m0 + jj) * 64 + 32 + rb) = a1;

    f32x4 acc[4];
    #pragma unroll
    for (int nt = 0; nt < 4; ++nt) {
        f32x4 z = {0.f, 0.f, 0.f, 0.f};
        z = __builtin_amdgcn_mfma_f32_16x16x32_bf16(a0, b1f[nt][0], z, 0, 0, 0);
        acc[nt] = __builtin_amdgcn_mfma_f32_16x16x32_bf16(a1, b1f[nt][1], z, 0, 0, 0);
    }
    #pragma unroll
    for (int nt = 0; nt < 4; ++nt) {
        #pragma unroll
        for (int r = 0; r < 4; ++r) {
            float h = acc[nt][r] + b1v[nt];
            h = (h >= 0.f) ? h : 0.1f * h;
            hrow[(rowC + r) * 64 + nt * 16 + jj] = f2bf(h);
        }
    }
    bf16x8 ha0 = *(bf16x8*)(hrow + jj * 64 + rb);
    bf16x8 ha1 = *(bf16x8*)(hrow + jj * 64 + 32 + rb);

    #pragma unroll
    for (int nt = 0; nt < 8; ++nt) {
        f32x4 z = {0.f, 0.f, 0.f, 0.f};
        z = __builtin_amdgcn_mfma_f32_16x16x32_bf16(ha0, b2f[nt][0], z, 0, 0, 0);
        f32x4 c2 = __builtin_amdgcn_mfma_f32_16x16x32_bf16(ha1, b2f[nt][1], z, 0, 0, 0);
        const int j = nt * 16 + jj;
        if (j < 120) {
            #pragma unroll
            for (int r = 0; r < 4; ++r)
                modw[(size_t)(m0 + rowC + r) * 120 + j] = 1.f / (1.f + __expf(-c2[r]));
        }
    }
}

// ---------------------------------------------------------------- phase 2 (v3)
__global__ __launch_bounds__(256, 4)
void kp_gather_v3(const float* __restrict__ q_pts,
                  const float* __restrict__ s_pts,
                  const u16*   __restrict__ fb,
                  const int*   __restrict__ neighb_inds,
                  const float* __restrict__ kpts,
                  const float* __restrict__ weights,
                  const float* __restrict__ modw,
                  float* __restrict__ out)
{
    __shared__ float wt_lds[15 * 64];
    const int tid = threadIdx.x;
    if (tid < 240) ((float4*)wt_lds)[tid] = ((const float4*)weights)[tid];
    __syncthreads();

    const int lane = tid & 63;
    const int wid  = tid >> 6;
    const int pair = blockIdx.x * 4 + wid;   // 16000 pairs exactly
    const int m0 = pair * 2;

    // ---- coalesced index load: lane = q*32 + h ----
    const int ind = __builtin_nontemporal_load(&neighb_inds[(size_t)m0 * 32 + lane]);

    // ---- issue 8 row-gathers immediately (address needs only ind) ----
    const int cdiv = lane & 7;     // channel block: c = cdiv*8 + e
    const int hl   = lane >> 3;    // neighbor slot within chunk
    bf16x8 fv[2][4];
    #pragma unroll
    for (int qq = 0; qq < 2; ++qq)
        #pragma unroll
        for (int cc = 0; cc < 4; ++cc) {
            const int ih = __shfl(ind, qq * 32 + cc * 8 + hl);
            fv[qq][cc] = *(const bf16x8*)(fb + (size_t)(u32)ih * 64 + cdiv * 8);
        }

    // ---- modulation rows, coalesced (overlap with gather latency) ----
    const size_t mb0 = (size_t)m0 * 120, mb1 = mb0 + 120;
    const float vA0 = __builtin_nontemporal_load(&modw[mb0 + lane]);
    const float vB0 = (lane < 56) ? __builtin_nontemporal_load(&modw[mb0 + 64 + lane]) : 0.f;
    const float vA1 = __builtin_nontemporal_load(&modw[mb1 + lane]);
    const float vB1 = (lane < 56) ? __builtin_nontemporal_load(&modw[mb1 + 64 + lane]) : 0.f;

    // ---- influence (runs under gather latency): lane = q*32 + h ----
    const int q = lane >> 5;
    const int m = m0 + q;
    const float qx = q_pts[m * 3 + 0];
    const float qy = q_pts[m * 3 + 1];
    const float qz = q_pts[m * 3 + 2];
    const float px = s_pts[(size_t)ind * 3 + 0] - qx;
    const float py = s_pts[(size_t)ind * 3 + 1] - qy;
    const float pz = s_pts[(size_t)ind * 3 + 2] - qz;
    float best = 1e30f; int bk = 0;
    #pragma unroll
    for (int k = 0; k < 15; ++k) {            // kpts -> uniform SGPR loads
        float ex = px - kpts[k * 3 + 0];
        float ey = py - kpts[k * 3 + 1];
        float ez = pz - kpts[k * 3 + 2];
        float d2 = fmaf(ex, ex, fmaf(ey, ey, ez * ez));
        if (d2 < best) { best = d2; bk = k; } // strict < = first-min (argmin rule)
    }
    const float infl = fmaxf(0.f, 1.f - sqrtf(best));   // SIGMA = 1

    // ---- consume: acc[q][e] over 4 chunks; butterfly over hl afterwards ----
    float acc[2][8];
    #pragma unroll
    for (int qq = 0; qq < 2; ++qq)
        #pragma unroll
        for (int e = 0; e < 8; ++e) acc[qq][e] = 0.f;

    #pragma unroll
    for (int qq = 0; qq < 2; ++qq) {
        #pragma unroll
        for (int cc = 0; cc < 4; ++cc) {
            const int idx = qq * 32 + cc * 8 + hl;
            const int kh  = __shfl(bk, idx);
            const float fl = __shfl(infl, idx);
            const int j = kh * 8 + cdiv;                  // mod slot for all 8 channels
            const float svA = __shfl(qq ? vA1 : vA0, j & 63);
            const float svB = __shfl(qq ? vB1 : vB0, (j - 64) & 63);
            const float w = ((j < 64) ? svA : svB) * fl;
            const float4 wa = *(const float4*)&wt_lds[kh * 64 + cdiv * 8];
            const float4 wb = *(const float4*)&wt_lds[kh * 64 + cdiv * 8 + 4];
            const bf16x8 f8 = fv[qq][cc];
            acc[qq][0] = fmaf(bf2f((u16)f8[0]), wa.x * w, acc[qq][0]);
            acc[qq][1] = fmaf(bf2f((u16)f8[1]), wa.y * w, acc[qq][1]);
            acc[qq][2] = fmaf(bf2f((u16)f8[2]), wa.z * w, acc[qq][2]);
            acc[qq][3] = fmaf(bf2f((u16)f8[3]), wa.w * w, acc[qq][3]);
            acc[qq][4] = fmaf(bf2f((u16)f8[4]), wb.x * w, acc[qq][4]);
            acc[qq][5] = fmaf(bf2f((u16)f8[5]), wb.y * w, acc[qq][5]);
            acc[qq][6] = fmaf(bf2f((u16)f8[6]), wb.z * w, acc[qq][6]);
            acc[qq][7] = fmaf(bf2f((u16)f8[7]), wb.w * w, acc[qq][7]);
        }
    }

    // ---- butterfly reduce over hl (lane bits 3..5) ----
    #pragma unroll
    for (int step = 8; step <= 32; step <<= 1)
        #pragma unroll
        for (int qq = 0; qq < 2; ++qq)
            #pragma unroll
            for (int e = 0; e < 8; ++e)
                acc[qq][e] += __shfl_xor(acc[qq][e], step);

    if (hl == 0) {
        #pragma unroll
        for (int qq = 0; qq < 2; ++qq) {
            f32x4 o0 = {acc[qq][0], acc[qq][1], acc[qq][2], acc[qq][3]};
            f32x4 o1 = {acc[qq][4], acc[qq][5], acc[qq][6], acc[qq][7]};
            float* dst = out + (size_t)(m0 + qq) * 64 + cdiv * 8;
            __builtin_nontemporal_store(o0, (f32x4*)dst);
            __builtin_nontemporal_store(o1, (f32x4*)(dst + 4));
        }
    }
}

// ------------------- fallback tier: proven f32 path -------------------
__global__ __launch_bounds__(256, 3)
void mod_mlp(const float* __restrict__ s_feats,
             const float* __restrict__ w1,
             const float* __restrict__ b1,
             const float* __restrict__ w2,
             float* __restrict__ modw)
{
    __shared__ float w1_lds[64 * 64];
    __shared__ float w2_lds[64 * 120 + 8];

    const int tid = threadIdx.x;
    {
        const float4* s1 = (const float4*)w1;
        float4* d1 = (float4*)w1_lds;
        #pragma unroll
        for (int i = 0; i < 4; ++i) d1[tid + 256 * i] = s1[tid + 256 * i];
        const float4* s2 = (const float4*)w2;
        float4* d2 = (float4*)w2_lds;
        for (int i = tid; i < (64 * 120) / 4; i += 256) d2[i] = s2[i];
        if (tid < 8) w2_lds[64 * 120 + tid] = 0.f;
    }
    __syncthreads();

    const int lane = tid & 63;
    const int wid  = tid >> 6;
    const int c    = lane;
    const int nwaves = gridDim.x * 4;
    const int gwave  = blockIdx.x * 4 + wid;
    const float b1v = b1[c];
    const int cB = 64 + ((c < 56) ? c : 55);

    for (int pair = gwave; pair * 2 < MQ; pair += nwaves) {
        const int m0 = pair * 2;
        float f0 = s_feats[(size_t)m0 * 64 + c];
        float f1 = s_feats[(size_t)(m0 + 1) * 64 + c];
        float h0a = b1v, h0b = 0.f, h1a = b1v, h1b = 0.f;
        #pragma unroll
        for (int i = 0; i < 64; i += 2) {
            float wa = w1_lds[i * 64 + c];
            float wb = w1_lds[(i + 1) * 64 + c];
            h0a = fmaf(rlf(f0, i), wa, h0a);
            h0b = fmaf(rlf(f0, i + 1), wb, h0b);
            h1a = fmaf(rlf(f1, i), wa, h1a);
            h1b = fmaf(rlf(f1, i + 1), wb, h1b);
        }
        float h0 = h0a + h0b, h1 = h1a + h1b;
        h0 = (h0 >= 0.f) ? h0 : 0.1f * h0;
        h1 = (h1 >= 0.f) ? h1 : 0.1f * h1;
        float a00 = 0.f, a01 = 0.f, a10 = 0.f, a11 = 0.f;
        #pragma unroll
        for (int i = 0; i < 64; ++i) {
            float wA = w2_lds[i * 120 + c];
            float wB = w2_lds[i * 120 + cB];
            float s0 = rlf(h0, i);
            float s1 = rlf(h1, i);
            a00 = fmaf(s0, wA, a00);
            a01 = fmaf(s0, wB, a01);
            a10 = fmaf(s1, wA, a10);
            a11 = fmaf(s1, wB, a11);
        }
        modw[(size_t)m0 * 120 + c]       = 1.f / (1.f + __expf(-a00));
        modw[(size_t)(m0 + 1) * 120 + c] = 1.f / (1.f + __expf(-a10));
        if (c < 56) {
            modw[(size_t)m0 * 120 + 64 + c]       = 1.f / (1.f + __expf(-a01));
            modw[(size_t)(m0 + 1) * 120 + 64 + c] = 1.f / (1.f + __expf(-a11));
        }
    }
}

__global__ __launch_bounds__(256, 4)
void kp_gather(const float* __restrict__ q_pts,
               const float* __restrict__ s_pts,
               const float* __restrict__ s_feats,
               const int*   __restrict__ neighb_inds,
               const float* __restrict__ kpts,
               const float* __restrict__ weights,
               const float* __restrict__ modw,
               float* __restrict__ out)
{
    __shared__ float wt_lds[15 * 64];
    const int tid = threadIdx.x;
    if (tid < 240) ((float4*)wt_lds)[tid] = ((const float4*)weights)[tid];
    __syncthreads();

    const int lane = tid & 63;
    const int wid  = tid >> 6;
    const int c    = lane;
    const int u    = c >> 3;
    const int pair = blockIdx.x * 4 + wid;
    const int m0 = pair * 2;

    const int q = lane >> 5;
    const int m = m0 + q;
    const int ind = neighb_inds[(size_t)m0 * 32 + lane];
    const float qx = q_pts[m * 3 + 0];
    const float qy = q_pts[m * 3 + 1];
    const float qz = q_pts[m * 3 + 2];
    const float px = s_pts[(size_t)ind * 3 + 0] - qx;
    const float py = s_pts[(size_t)ind * 3 + 1] - qy;
    const float pz = s_pts[(size_t)ind * 3 + 2] - qz;
    float best = 1e30f; int bk = 0;
    #pragma unroll
    for (int k = 0; k < 15; ++k) {
        float ex = px - kpts[k * 3 + 0];
        float ey = py - kpts[k * 3 + 1];
        float ez = pz - kpts[k * 3 + 2];
        float d2 = fmaf(ex, ex, fmaf(ey, ey, ez * ez));
        if (d2 < best) { best = d2; bk = k; }
    }
    const float infl = fmaxf(0.f, 1.f - sqrtf(best));
    const int pk = (ind << 4) | bk;

    const size_t mb0 = (size_t)m0 * 120, mb1 = mb0 + 120;
    const float vA0 = modw[mb0 + c];
    const float vB0 = (c < 56) ? modw[mb0 + 64 + c] : 0.f;
    const float vA1 = modw[mb1 + c];
    const float vB1 = (c < 56) ? modw[mb1 + 64 + c] : 0.f;

    float fv0[32], fv1[32];
    #pragma unroll
    for (int h = 0; h < 32; ++h)
        fv0[h] = s_feats[(size_t)(rli(pk, h) >> 4) * 64 + c];
    #pragma unroll
    for (int h = 0; h < 32; ++h)
        fv1[h] = s_feats[(size_t)(rli(pk, 32 + h) >> 4) * 64 + c];

    float p0 = 0.f, p1 = 0.f, p2 = 0.f, p3 = 0.f;
    #pragma unroll
    for (int h = 0; h < 32; h += 4) {
        #pragma unroll
        for (int j = 0; j < 4; ++j) {
            const int s = rli(pk, h + j);
            const int kh = s & 15;
            const float fl = rlf(infl, h + j);
            const float sv = (kh < 8) ? __shfl(vA0, (kh << 3) + u)
                                      : __shfl(vB0, ((kh - 8) << 3) + u);
            const float w = wt_lds[(kh << 6) + c] * sv * fl;
            float& p = (j == 0) ? p0 : (j == 1) ? p1 : (j == 2) ? p2 : p3;
            p = fmaf(fv0[h + j], w, p);
        }
    }
    const float acc0 = (p0 + p1) + (p2 + p3);

    float r0 = 0.f, r1 = 0.f, r2 = 0.f, r3 = 0.f;
    #pragma unroll
    for (int h = 0; h < 32; h += 4) {
        #pragma unroll
        for (int j = 0; j < 4; ++j) {
            const int s = rli(pk, 32 + h + j);
            const int kh = s & 15;
            const float fl = rlf(infl, 32 + h + j);
            const float sv = (kh < 8) ? __shfl(vA1, (kh << 3) + u)
                                      : __shfl(vB1, ((kh - 8) << 3) + u);
            const float w = wt_lds[(kh << 6) + c] * sv * fl;
            float& p = (j == 0) ? r0 : (j == 1) ? r1 : (j == 2) ? r2 : r3;
            p = fmaf(fv1[h + j], w, p);
        }
    }
    const float acc1 = (r0 + r1) + (r2 + r3);

    out[(size_t)m0 * 64 + c]       = acc0;
    out[(size_t)(m0 + 1) * 64 + c] = acc1;
}

extern "C" void kernel_launch(void* const* d_in, const int* in_sizes, int n_in,
                              void* d_out, int out_size, void* d_ws, size_t ws_size,
                              hipStream_t stream) {
    const float* q_pts       = (const float*)d_in[0];
    const float* s_pts       = (const float*)d_in[1];
    const float* s_feats     = (const float*)d_in[2];
    const int*   neighb_inds = (const int*)d_in[3];
    const float* kpts        = (const float*)d_in[4];
    const float* weights     = (const float*)d_in[5];
    const float* w1          = (const float*)d_in[6];
    const float* b1          = (const float*)d_in[7];
    const float* w2          = (const float*)d_in[8];
    float* out = (float*)d_out;

    const size_t needFB   = (size_t)MQ * 64 * sizeof(u16);     // 4.096 MB
    const size_t needMODW = (size_t)MQ * 120 * sizeof(float);  // 15.36 MB
    if (ws_size >= needFB + needMODW) {
        u16*   fb   = (u16*)d_ws;
        float* modw = (float*)((char*)d_ws + needFB);
        mod_mlp_mfma<<<500, 256, 0, stream>>>(s_feats, w1, b1, w2, modw, fb);
        kp_gather_v3<<<MQ / 8, 256, 0, stream>>>(q_pts, s_pts, fb, neighb_inds,
                                                 kpts, weights, modw, out);
    } else {
        float* modw = (float*)d_ws;
        mod_mlp<<<768, 256, 0, stream>>>(s_feats, w1, b1, w2, modw);
        kp_gather<<<MQ / 8, 256, 0, stream>>>(q_pts, s_pts, s_feats, neighb_inds,
                                              kpts, weights, modw, out);
    }
}